// Round 12
// baseline (253.327 us; speedup 1.0000x reference)
//
#include <hip/hip_runtime.h>
#include <hip/hip_bf16.h>

// Problem constants
#define BB 8
#define NN 4096
#define EE 65536            // edges per graph
#define BE (BB*EE)          // 524288 total edges
#define BN (BB*NN)          // 32768 total nodes
#define INF 128
#define HID 512
#define CC 2
#define OUTC 10
#define ELLCAP 64           // max in-degree capacity (Binomial mean 16, P(>=64)<1e-13)

typedef __bf16 bf16x8_t __attribute__((ext_vector_type(8)));
typedef float  f32x4_t  __attribute__((ext_vector_type(4)));

__device__ __forceinline__ ushort f2bf(float f) {
  union { float f; unsigned u; } v; v.f = f;
  unsigned r = v.u + 0x7FFFu + ((v.u >> 16) & 1u);   // RNE
  return (ushort)(r >> 16);
}
__device__ __forceinline__ float bf2f(ushort s) {
  union { unsigned u; float f; } v; v.u = ((unsigned)s) << 16;
  return v.f;
}

// ---------------------------------------------------------------------------
// Kernel FRONT (fused): three independent prep stages in one launch.
//   blk <  4096        : cast_x  (x fp32 -> Ab[:,128:256] bf16)
//   4096 <= blk < 6144 : ell_build (one 8B int2 store per edge, 1 atomic)
//   6144 <= blk        : cast_w  (pre-transposed bf16 weights)
// Overlaps the atomic-latency ELL build with the BW-bound casts.
// ---------------------------------------------------------------------------
__global__ __launch_bounds__(256) void front(
    const int* __restrict__ src, const int* __restrict__ dst,
    const float* __restrict__ ew, const float* __restrict__ x,
    const float* __restrict__ Wrel, const float* __restrict__ Wroot,
    int* __restrict__ deg, int2* __restrict__ ell,
    ushort* __restrict__ Ab, ushort* __restrict__ Bb) {
  int blk = blockIdx.x;
  int tid = threadIdx.x;
  if (blk < 4096) {
    int g = blk * 256 + tid;                   // 0..1048575
    float4 v = *(const float4*)&x[(size_t)g * 4];
    int m = g >> 5;
    int kin = (g & 31) * 4;
    ushort4 o;
    o.x = f2bf(v.x); o.y = f2bf(v.y); o.z = f2bf(v.z); o.w = f2bf(v.w);
    *(ushort4*)&Ab[(size_t)m * 256 + 128 + kin] = o;
  } else if (blk < 6144) {
    int e = (blk - 4096) * 256 + tid;          // 0..524287
    int d = dst[e];
    int p = atomicAdd(&deg[d], 1);
    if (p < ELLCAP) {
      int2 v; v.x = src[e]; v.y = __float_as_int(ew[e]);
      ell[(size_t)d * ELLCAP + p] = v;
    }
  } else {
    int g = (blk - 6144) * 256 + tid;          // 0..131071
    int n = g & 511, k = g >> 9;
    float w = (k < 128) ? Wrel[k * 512 + n] : Wroot[(k - 128) * 512 + n];
    Bb[n * 256 + k] = f2bf(w);
  }
}

// ---------------------------------------------------------------------------
// Kernel A4: gather  A[n, 0:128] = bf16( sum_j w_j * xbf16[src_j,:] )
// ELL entries are packed int2 (src, w-bits): one 8B load per edge.
// ---------------------------------------------------------------------------
__global__ __launch_bounds__(256) void gather_ell(
    const int* __restrict__ deg, const int2* __restrict__ ell,
    ushort* __restrict__ Ab) {
  int n = blockIdx.x * 4 + (threadIdx.x >> 6);
  int lane = threadIdx.x & 63;
  int d = deg[n]; if (d > ELLCAP) d = ELLCAP;
  const int2* ep = ell + (size_t)n * ELLCAP;
  float ax = 0.f, ay = 0.f;
  int j = 0;
  for (; j + 1 < d; j += 2) {
    int2 v0 = ep[j], v1 = ep[j + 1];
    float w0 = __int_as_float(v0.y), w1 = __int_as_float(v1.y);
    ushort2 u0 = *(const ushort2*)&Ab[(size_t)v0.x * 256 + 128 + lane * 2];
    ushort2 u1 = *(const ushort2*)&Ab[(size_t)v1.x * 256 + 128 + lane * 2];
    ax += w0 * bf2f(u0.x) + w1 * bf2f(u1.x);
    ay += w0 * bf2f(u0.y) + w1 * bf2f(u1.y);
  }
  if (j < d) {
    int2 v0 = ep[j];
    float w0 = __int_as_float(v0.y);
    ushort2 u0 = *(const ushort2*)&Ab[(size_t)v0.x * 256 + 128 + lane * 2];
    ax += w0 * bf2f(u0.x);
    ay += w0 * bf2f(u0.y);
  }
  ushort2 o; o.x = f2bf(ax); o.y = f2bf(ay);
  *(ushort2*)&Ab[(size_t)n * 256 + lane * 2] = o;
}

// ---------------------------------------------------------------------------
// Kernel C: MFMA GEMM, B-in-registers variant. 64x64 tile, full K=256.
// A staged in 32 KB XOR-swizzled LDS (-> 4 blocks/CU vs 2); B fragments
// preloaded to 64 VGPRs from the L2-hot 256 KB Bb. One barrier before MFMA.
// Epilogue: C -> LDS (reuse As) -> 16B/lane coalesced global stores
// (fixes the 2-byte scattered-store write amplification seen in R4).
// ---------------------------------------------------------------------------
__global__ __launch_bounds__(256) void gemm_mfma(
    const ushort* __restrict__ Ab, const ushort* __restrict__ Bb,
    const float* __restrict__ brel, ushort* __restrict__ hw) {
  __shared__ ushort As[64 * 256];   // 32 KB
  int tid = threadIdx.x;
  int blk = blockIdx.x;
  int xcd = blk & 7;
  int idx = blk >> 3;                  // 0..511
  int by = xcd * 64 + (idx & 63);      // 0..511
  int bx = idx >> 6;                   // 0..7
  int m0 = by * 64, n0 = bx * 64;
  int wave = tid >> 6, lane = tid & 63;
  int wm = (wave >> 1) * 32, wn = (wave & 1) * 32;
  int l16 = lane & 15, quad = lane >> 4;

  // preload B fragments into registers (16 x 16B global loads, independent)
  bf16x8_t bfr[2][8];
#pragma unroll
  for (int g = 0; g < 2; ++g) {
    int row = n0 + wn + g * 16 + l16;
#pragma unroll
    for (int kc = 0; kc < 8; ++kc)
      bfr[g][kc] = *(const bf16x8_t*)&Bb[(size_t)row * 256 + kc * 32 + quad * 8];
  }

  // stage A (XOR-swizzled chunks)
#pragma unroll
  for (int i = 0; i < 8; ++i) {
    int g = tid + i * 256;
    int r = g >> 5, c = g & 31;
    int cs = c ^ (r & 31);
    *(uint4*)&As[(r * 32 + cs) * 8] = *(const uint4*)&Ab[(size_t)(m0 + r) * 256 + c * 8];
  }
  __syncthreads();

  f32x4_t acc[2][2];
#pragma unroll
  for (int f = 0; f < 2; ++f)
#pragma unroll
    for (int g = 0; g < 2; ++g) acc[f][g] = (f32x4_t){0.f, 0.f, 0.f, 0.f};

  int arow[2] = {wm + l16, wm + 16 + l16};
#pragma unroll
  for (int kc = 0; kc < 8; ++kc) {
    int cl = kc * 4 + quad;
    bf16x8_t af[2];
#pragma unroll
    for (int f = 0; f < 2; ++f)
      af[f] = *(const bf16x8_t*)&As[(arow[f] * 32 + (cl ^ (arow[f] & 31))) * 8];
#pragma unroll
    for (int f = 0; f < 2; ++f)
#pragma unroll
      for (int g = 0; g < 2; ++g)
        acc[f][g] = __builtin_amdgcn_mfma_f32_16x16x32_bf16(af[f], bfr[g][kc], acc[f][g], 0, 0, 0);
  }
  __syncthreads();   // all A reads done; reuse As as C staging

  ushort* Cs = As;   // 64x64 bf16 = 8 KB
#pragma unroll
  for (int g = 0; g < 2; ++g) {
    int col = wn + g * 16 + l16;
    float bias = brel[n0 + col];
#pragma unroll
    for (int f = 0; f < 2; ++f) {
      int rowb = wm + f * 16 + quad * 4;
#pragma unroll
      for (int r = 0; r < 4; ++r) {
        float v = fmaxf(acc[f][g][r] + bias, 0.f);
        Cs[(rowb + r) * 64 + col] = f2bf(v);
      }
    }
  }
  __syncthreads();
  {
    int r = tid >> 2, co = (tid & 3) * 16;
    uint4 v0 = *(uint4*)&Cs[r * 64 + co];
    uint4 v1 = *(uint4*)&Cs[r * 64 + co + 8];
    *(uint4*)&hw[(size_t)(m0 + r) * 512 + n0 + co] = v0;
    *(uint4*)&hw[(size_t)(m0 + r) * 512 + n0 + co + 8] = v1;
  }
}

// ---------------------------------------------------------------------------
// Kernel D+F fused: per node s (softmax of h.Wpool+b), s/s_logits stores,
// out[b,c,:] partials in registers -> plain stores to outpart (no atomics).
// ---------------------------------------------------------------------------
__global__ __launch_bounds__(256) void pool_node(
    const ushort* __restrict__ hw, const float* __restrict__ Wp,
    const float* __restrict__ bp, float* __restrict__ s,
    float* __restrict__ slog, float* __restrict__ outpart,
    float* __restrict__ ssacc) {
  __shared__ float red[4][1024];   // 16 KB
  __shared__ float ssr[4][3];
  int blk = blockIdx.x;            // 512 blocks
  int b = blk >> 6;
  int wave = threadIdx.x >> 6, lane = threadIdx.x & 63;
  int n0 = blk * 64 + wave * 16;
  int f0 = lane * 8;

  float wp0[8], wp1[8];
#pragma unroll
  for (int j = 0; j < 8; ++j) {
    wp0[j] = Wp[(f0 + j) * 2];
    wp1[j] = Wp[(f0 + j) * 2 + 1];
  }
  float bp0 = bp[0], bp1 = bp[1];
  float o0[8] = {0, 0, 0, 0, 0, 0, 0, 0};
  float o1[8] = {0, 0, 0, 0, 0, 0, 0, 0};
  float sa = 0.f, sb = 0.f, sc2 = 0.f;

  for (int i = 0; i < 16; ++i) {
    int n = n0 + i;
    bf16x8_t hv = *(const bf16x8_t*)&hw[(size_t)n * HID + f0];
    const ushort* hp = (const ushort*)&hv;
    float h[8];
    float a0 = 0.f, a1 = 0.f;
#pragma unroll
    for (int j = 0; j < 8; ++j) {
      h[j] = bf2f(hp[j]);
      a0 += h[j] * wp0[j];
      a1 += h[j] * wp1[j];
    }
#pragma unroll
    for (int off = 32; off; off >>= 1) {
      a0 += __shfl_down(a0, off, 64);
      a1 += __shfl_down(a1, off, 64);
    }
    float s0 = 0.f, s1 = 0.f;
    if (lane == 0) {
      float l0 = a0 + bp0, l1 = a1 + bp1;
      slog[n * 2] = l0;
      slog[n * 2 + 1] = l1;
      float m = fmaxf(l0, l1);
      float e0 = expf(l0 - m), e1 = expf(l1 - m);
      float inv = 1.f / (e0 + e1);
      s0 = e0 * inv; s1 = e1 * inv;
      s[n * 2] = s0;
      s[n * 2 + 1] = s1;
      sa += s0 * s0; sb += s0 * s1; sc2 += s1 * s1;
    }
    s0 = __shfl(s0, 0, 64);
    s1 = __shfl(s1, 0, 64);
#pragma unroll
    for (int j = 0; j < 8; ++j) {
      o0[j] += s0 * h[j];
      o1[j] += s1 * h[j];
    }
  }

#pragma unroll
  for (int j = 0; j < 8; ++j) {
    red[wave][f0 + j] = o0[j];
    red[wave][512 + f0 + j] = o1[j];
  }
  if (lane == 0) { ssr[wave][0] = sa; ssr[wave][1] = sb; ssr[wave][2] = sc2; }
  __syncthreads();
  int t = threadIdx.x;
#pragma unroll
  for (int q = 0; q < 4; ++q) {
    int idx = t + q * 256;
    float v = red[0][idx] + red[1][idx] + red[2][idx] + red[3][idx];
    outpart[(size_t)blk * 1024 + idx] = v;
  }
  if (t < 3) {
    float v = ssr[0][t] + ssr[1][t] + ssr[2][t] + ssr[3][t];
    atomicAdd(&ssacc[b * 4 + t], v);
  }
}

// ---------------------------------------------------------------------------
// Kernel E: out_adj_raw[b,i,j] = sum_e w_e * s[src,i] * s[dst,j]
// + mincut_den[b] = sum_e w_e * (s0[src]^2 + s1[src]^2)
// ---------------------------------------------------------------------------
__global__ __launch_bounds__(256) void edge_pass2(
    const int* __restrict__ src, const int* __restrict__ dst,
    const float* __restrict__ ew, const float* __restrict__ s,
    float* __restrict__ oadj, float* __restrict__ mden) {
  int b = blockIdx.x >> 6;
  int sub = blockIdx.x & 63;
  int base = b * EE + sub * 1024;
  float p00 = 0, p01 = 0, p10 = 0, p11 = 0, md = 0;
  for (int i = threadIdx.x; i < 1024; i += 256) {
    int e = base + i;
    int r = src[e], c = dst[e];
    float w = ew[e];
    float s0r = s[r * 2], s1r = s[r * 2 + 1];
    float s0c = s[c * 2], s1c = s[c * 2 + 1];
    p00 += w * s0r * s0c; p01 += w * s0r * s1c;
    p10 += w * s1r * s0c; p11 += w * s1r * s1c;
    md  += w * (s0r * s0r + s1r * s1r);
  }
#pragma unroll
  for (int off = 32; off; off >>= 1) {
    p00 += __shfl_down(p00, off, 64);
    p01 += __shfl_down(p01, off, 64);
    p10 += __shfl_down(p10, off, 64);
    p11 += __shfl_down(p11, off, 64);
    md  += __shfl_down(md,  off, 64);
  }
  __shared__ float red[4][5];
  int wave = threadIdx.x >> 6, lane = threadIdx.x & 63;
  if (lane == 0) {
    red[wave][0] = p00; red[wave][1] = p01;
    red[wave][2] = p10; red[wave][3] = p11;
    red[wave][4] = md;
  }
  __syncthreads();
  if (threadIdx.x < 4) {
    float v = red[0][threadIdx.x] + red[1][threadIdx.x] +
              red[2][threadIdx.x] + red[3][threadIdx.x];
    atomicAdd(&oadj[b * 4 + threadIdx.x], v);
  } else if (threadIdx.x == 4) {
    float v = red[0][4] + red[1][4] + red[2][4] + red[3][4];
    atomicAdd(&mden[b], v);
  }
}

// ---------------------------------------------------------------------------
// Kernel G1: per-graph scalars + build u,v vectors (sums outpart partials).
// ---------------------------------------------------------------------------
__global__ __launch_bounds__(256) void finalize_a(
    const float* __restrict__ outpart, const float* __restrict__ oadj,
    const float* __restrict__ ssacc, const float* __restrict__ mden,
    float* __restrict__ uv, float* __restrict__ dout) {
  __shared__ float sc[2];
  int b = blockIdx.x, t = threadIdx.x;
  if (t == 0) {
    float r00 = oadj[b * 4 + 0], r01 = oadj[b * 4 + 1];
    float r10 = oadj[b * 4 + 2], r11 = oadj[b * 4 + 3];
    atomicAdd(&dout[80], -((r00 + r11) / mden[b]) / (float)BB);
    float a = ssacc[b * 4 + 0], bb = ssacc[b * 4 + 1], c = ssacc[b * 4 + 2];
    float nrm = sqrtf(a * a + 2.f * bb * bb + c * c);
    float q = 0.70710678118654752f;
    float da = a / nrm - q, db = bb / nrm, dc = c / nrm - q;
    atomicAdd(&dout[81], sqrtf(da * da + 2.f * db * db + dc * dc) / (float)BB);
    float d20 = sqrtf(r01) + 1e-15f;
    float d21 = sqrtf(r10) + 1e-15f;
    float oa01 = r01 / (d20 * d21);
    float oa10 = r10 / (d21 * d20);
    dout[65618 + b * 4 + 0] = 0.f;
    dout[65618 + b * 4 + 1] = oa01;
    dout[65618 + b * 4 + 2] = oa10;
    dout[65618 + b * 4 + 3] = 0.f;
    sc[0] = oa01; sc[1] = oa10;
  }
  __syncthreads();
  float oa01 = sc[0], oa10 = sc[1];
  for (int f = t; f < HID; f += 256) {
    float o0 = 0.f, o1 = 0.f;
    for (int i = 0; i < 64; ++i) {
      o0 += outpart[(size_t)(b * 64 + i) * 1024 + f];
      o1 += outpart[(size_t)(b * 64 + i) * 1024 + 512 + f];
    }
    uv[b * HID + f] = oa10 * o1 + oa01 * o0;           // u
    uv[BB * HID + b * HID + f] = o0 + o1;              // v
  }
}

// ---------------------------------------------------------------------------
// Kernel G2: conv3 split-K partials. Grid 128 = kc(16) x fc(8).
// ---------------------------------------------------------------------------
__global__ __launch_bounds__(256) void conv3_part(
    const float* __restrict__ uv, const float* __restrict__ Wrel3,
    const float* __restrict__ Wroot3, float* __restrict__ xmacc) {
  __shared__ float us[8][32], vs[8][32];
  __shared__ float red[4][64][8];
  int blk = blockIdx.x;
  int fc = blk & 7, kc = blk >> 3;
  int t = threadIdx.x;
  {
    int b = t >> 5, k = t & 31;
    us[b][k] = uv[b * HID + kc * 32 + k];
    vs[b][k] = uv[BB * HID + b * HID + kc * 32 + k];
  }
  __syncthreads();
  int f = fc * 64 + (t & 63);
  int ks = t >> 6;                 // 0..3
  float acc[8] = {0, 0, 0, 0, 0, 0, 0, 0};
#pragma unroll
  for (int j = 0; j < 8; ++j) {
    int kl = ks * 8 + j;           // 0..31
    int k = kc * 32 + kl;
    float wr = Wrel3[k * HID + f];
    float wo = Wroot3[k * HID + f];
#pragma unroll
    for (int b = 0; b < 8; ++b)
      acc[b] += us[b][kl] * wr + vs[b][kl] * wo;
  }
#pragma unroll
  for (int b = 0; b < 8; ++b) red[ks][t & 63][b] = acc[b];
  __syncthreads();
  if (ks == 0) {
    int fl = t & 63;
#pragma unroll
    for (int b = 0; b < 8; ++b) {
      float v = red[0][fl][b] + red[1][fl][b] + red[2][fl][b] + red[3][fl][b];
      atomicAdd(&xmacc[b * HID + f], v);
    }
  }
}

// ---------------------------------------------------------------------------
// Kernel G3: lin1 split-K partials; xm = 0.5*xmacc + brel3 at staging.
// ---------------------------------------------------------------------------
__global__ __launch_bounds__(256) void lin1_part(
    const float* __restrict__ xmacc, const float* __restrict__ brel3,
    const float* __restrict__ Wlin1, float* __restrict__ h2acc) {
  __shared__ float xs[8][32];
  __shared__ float red[4][64][8];
  int blk = blockIdx.x;
  int fc = blk & 7, kc = blk >> 3;
  int t = threadIdx.x;
  {
    int b = t >> 5, k = t & 31;
    xs[b][k] = 0.5f * xmacc[b * HID + kc * 32 + k] + brel3[kc * 32 + k];
  }
  __syncthreads();
  int f = fc * 64 + (t & 63);
  int ks = t >> 6;
  float acc[8] = {0, 0, 0, 0, 0, 0, 0, 0};
#pragma unroll
  for (int j = 0; j < 8; ++j) {
    int kl = ks * 8 + j;
    int k = kc * 32 + kl;
    float w = Wlin1[k * HID + f];
#pragma unroll
    for (int b = 0; b < 8; ++b)
      acc[b] += xs[b][kl] * w;
  }
#pragma unroll
  for (int b = 0; b < 8; ++b) red[ks][t & 63][b] = acc[b];
  __syncthreads();
  if (ks == 0) {
    int fl = t & 63;
#pragma unroll
    for (int b = 0; b < 8; ++b) {
      float v = red[0][fl][b] + red[1][fl][b] + red[2][fl][b] + red[3][fl][b];
      atomicAdd(&h2acc[b * HID + f], v);
    }
  }
}

// ---------------------------------------------------------------------------
// Kernel G4: logits + log_softmax; h2 = relu(h2acc + blin1) at staging.
// ---------------------------------------------------------------------------
__global__ __launch_bounds__(256) void head(
    const float* __restrict__ h2acc, const float* __restrict__ blin1,
    const float* __restrict__ Wlin2, const float* __restrict__ blin2,
    float* __restrict__ dout) {
  __shared__ float hs[HID];
  __shared__ float lg[16];
  __shared__ float lse;
  int b = blockIdx.x, t = threadIdx.x;
  for (int i = t; i < HID; i += 256)
    hs[i] = fmaxf(h2acc[b * HID + i] + blin1[i], 0.f);
  __syncthreads();
  int wave = t >> 6, lane = t & 63;
  for (int o = wave; o < OUTC; o += 4) {
    float acc = 0.f;
    for (int k = lane; k < HID; k += 64)
      acc += hs[k] * Wlin2[k * OUTC + o];
#pragma unroll
    for (int off = 32; off; off >>= 1) acc += __shfl_down(acc, off, 64);
    if (lane == 0) lg[o] = acc + blin2[o];
  }
  __syncthreads();
  if (t == 0) {
    float m = lg[0];
    for (int o = 1; o < OUTC; ++o) m = fmaxf(m, lg[o]);
    float se = 0.f;
    for (int o = 0; o < OUTC; ++o) se += expf(lg[o] - m);
    lse = m + logf(se);
  }
  __syncthreads();
  if (t < OUTC) dout[b * OUTC + t] = lg[t] - lse;
}

// ---------------------------------------------------------------------------
// Launcher
// ---------------------------------------------------------------------------
extern "C" void kernel_launch(void* const* d_in, const int* in_sizes, int n_in,
                              void* d_out, int out_size, void* d_ws, size_t ws_size,
                              hipStream_t stream) {
  const float* x      = (const float*)d_in[0];
  const int*   ei     = (const int*)d_in[1];
  const float* ew     = (const float*)d_in[3];
  const float* Wrel1  = (const float*)d_in[4];
  const float* brel1  = (const float*)d_in[5];
  const float* Wroot1 = (const float*)d_in[6];
  const float* Wpool  = (const float*)d_in[7];
  const float* bpool  = (const float*)d_in[8];
  const float* Wrel3  = (const float*)d_in[9];
  const float* brel3  = (const float*)d_in[10];
  const float* Wroot3 = (const float*)d_in[11];
  const float* Wlin1  = (const float*)d_in[12];
  const float* blin1  = (const float*)d_in[13];
  const float* Wlin2  = (const float*)d_in[14];
  const float* blin2  = (const float*)d_in[15];
  float* out = (float*)d_out;
  float* ws  = (float*)d_ws;

  // workspace layout (float units)
  float* oadj  = ws + 40960;                // [40960, 40992)
  float* ssacc = oadj + 32;                 // [40992, 41024)
  float* mden  = ssacc + 32;                // [41024, 41032)
  int*   deg   = (int*)(mden + 8);          // [41032, 73800)  zero-region end
  ushort* Ab   = (ushort*)(ws + 106568);    // 32768x256 bf16  [106568, 4300872)
  ushort* Bb   = (ushort*)(ws + 4300872);   // 512x256 bf16    [4300872, 4366408)
  ushort* hbf  = (ushort*)(ws + 4366408);   // 32768x512 bf16  [4366408, 12755016)
  float* xmacc = ws + 12755016;             // 4096
  float* h2acc = xmacc + 4096;              // 4096            [12759112, 12763208)
  float* outpart = ws + 12763208;           // 512*1024        [12763208, 13287496)
  // aliases (lifetimes by stream order):
  int2*  ell   = (int2*)(ws + 4366408);     // 32768*64 int2 (16.8MB) inside h region,
                                            // dead before gemm writes hbf
  float* s     = ws + 106568;               // overlays Ab; Ab dead after gemm
  float* uv    = (float*)deg;               // deg dead after gather_ell

  const int* src = ei;
  const int* dst = ei + BE;

  hipMemsetAsync(ws + 40960, 0, (size_t)32840 * sizeof(float), stream);
  hipMemsetAsync(xmacc, 0, (size_t)8192 * sizeof(float), stream);
  hipMemsetAsync(out + 80, 0, 2 * sizeof(float), stream);

  front      <<<6656, 256, 0, stream>>>(src, dst, ew, x, Wrel1, Wroot1,
                                        deg, ell, Ab, Bb);
  gather_ell <<<BN / 4, 256, 0, stream>>>(deg, ell, Ab);
  gemm_mfma  <<<4096, 256, 0, stream>>>(Ab, Bb, brel1, hbf);
  pool_node  <<<512, 256, 0, stream>>>(hbf, Wpool, bpool, s, out + 82, outpart, ssacc);
  edge_pass2 <<<BB * 64, 256, 0, stream>>>(src, dst, ew, s, oadj, mden);
  finalize_a <<<BB, 256, 0, stream>>>(outpart, oadj, ssacc, mden, uv, out);
  conv3_part <<<128, 256, 0, stream>>>(uv, Wrel3, Wroot3, xmacc);
  lin1_part  <<<128, 256, 0, stream>>>(xmacc, brel3, Wlin1, h2acc);
  head       <<<BB, 256, 0, stream>>>(h2acc, blin1, Wlin2, blin2, out);
}

// Round 13
// 239.829 us; speedup vs baseline: 1.0563x; 1.0563x over previous
//
#include <hip/hip_runtime.h>
#include <hip/hip_bf16.h>

// Problem constants
#define BB 8
#define NN 4096
#define EE 65536            // edges per graph
#define BE (BB*EE)          // 524288 total edges
#define BN (BB*NN)          // 32768 total nodes
#define INF 128
#define HID 512
#define CC 2
#define OUTC 10
#define ELLCAP 64           // max in-degree capacity (Binomial mean 16, P(>=64)<1e-13)

typedef __bf16 bf16x8_t __attribute__((ext_vector_type(8)));
typedef float  f32x4_t  __attribute__((ext_vector_type(4)));

__device__ __forceinline__ ushort f2bf(float f) {
  union { float f; unsigned u; } v; v.f = f;
  unsigned r = v.u + 0x7FFFu + ((v.u >> 16) & 1u);   // RNE
  return (ushort)(r >> 16);
}
__device__ __forceinline__ float bf2f(ushort s) {
  union { unsigned u; float f; } v; v.u = ((unsigned)s) << 16;
  return v.f;
}

// ---------------------------------------------------------------------------
// Kernel FRONT (fused): three independent prep stages in one launch.
//   blk <  4096        : cast_x  (x fp32 -> Ab[:,128:256] bf16)
//   4096 <= blk < 6144 : ell_build (one 8B int2 store per edge, 1 atomic)
//   6144 <= blk        : cast_w  (pre-transposed bf16 weights)
// ---------------------------------------------------------------------------
__global__ __launch_bounds__(256) void front(
    const int* __restrict__ src, const int* __restrict__ dst,
    const float* __restrict__ ew, const float* __restrict__ x,
    const float* __restrict__ Wrel, const float* __restrict__ Wroot,
    int* __restrict__ deg, int2* __restrict__ ell,
    ushort* __restrict__ Ab, ushort* __restrict__ Bb) {
  int blk = blockIdx.x;
  int tid = threadIdx.x;
  if (blk < 4096) {
    int g = blk * 256 + tid;                   // 0..1048575
    float4 v = *(const float4*)&x[(size_t)g * 4];
    int m = g >> 5;
    int kin = (g & 31) * 4;
    ushort4 o;
    o.x = f2bf(v.x); o.y = f2bf(v.y); o.z = f2bf(v.z); o.w = f2bf(v.w);
    *(ushort4*)&Ab[(size_t)m * 256 + 128 + kin] = o;
  } else if (blk < 6144) {
    int e = (blk - 4096) * 256 + tid;          // 0..524287
    int d = dst[e];
    int p = atomicAdd(&deg[d], 1);
    if (p < ELLCAP) {
      int2 v; v.x = src[e]; v.y = __float_as_int(ew[e]);
      ell[(size_t)d * ELLCAP + p] = v;
    }
  } else {
    int g = (blk - 6144) * 256 + tid;          // 0..131071
    int n = g & 511, k = g >> 9;
    float w = (k < 128) ? Wrel[k * 512 + n] : Wroot[(k - 128) * 512 + n];
    Bb[n * 256 + k] = f2bf(w);
  }
}

// ---------------------------------------------------------------------------
// Kernel A4: gather  A[n, 0:128] = bf16( sum_j w_j * xbf16[src_j,:] )
// ELL entries are packed int2 (src, w-bits): one 8B load per edge.
// ---------------------------------------------------------------------------
__global__ __launch_bounds__(256) void gather_ell(
    const int* __restrict__ deg, const int2* __restrict__ ell,
    ushort* __restrict__ Ab) {
  int n = blockIdx.x * 4 + (threadIdx.x >> 6);
  int lane = threadIdx.x & 63;
  int d = deg[n]; if (d > ELLCAP) d = ELLCAP;
  const int2* ep = ell + (size_t)n * ELLCAP;
  float ax = 0.f, ay = 0.f;
  int j = 0;
  for (; j + 1 < d; j += 2) {
    int2 v0 = ep[j], v1 = ep[j + 1];
    float w0 = __int_as_float(v0.y), w1 = __int_as_float(v1.y);
    ushort2 u0 = *(const ushort2*)&Ab[(size_t)v0.x * 256 + 128 + lane * 2];
    ushort2 u1 = *(const ushort2*)&Ab[(size_t)v1.x * 256 + 128 + lane * 2];
    ax += w0 * bf2f(u0.x) + w1 * bf2f(u1.x);
    ay += w0 * bf2f(u0.y) + w1 * bf2f(u1.y);
  }
  if (j < d) {
    int2 v0 = ep[j];
    float w0 = __int_as_float(v0.y);
    ushort2 u0 = *(const ushort2*)&Ab[(size_t)v0.x * 256 + 128 + lane * 2];
    ax += w0 * bf2f(u0.x);
    ay += w0 * bf2f(u0.y);
  }
  ushort2 o; o.x = f2bf(ax); o.y = f2bf(ay);
  *(ushort2*)&Ab[(size_t)n * 256 + lane * 2] = o;
}

// ---------------------------------------------------------------------------
// Kernel C: single-stage MFMA GEMM (R10 structure restored). 64x64 tile,
// FULL K=256 staged once for BOTH A and B (coalesced, XOR-swizzled, 64 KB,
// 2 blocks/CU), ONE barrier before MFMA. Epilogue keeps R12's coalesced
// C path but pads the staging tile to stride 72 (144B row stride rotates
// banks -> kills the 655K conflicts measured in R12).
// ---------------------------------------------------------------------------
#define CPAD 72
__global__ __launch_bounds__(256) void gemm_mfma(
    const ushort* __restrict__ Ab, const ushort* __restrict__ Bb,
    const float* __restrict__ brel, ushort* __restrict__ hw) {
  __shared__ ushort As[64 * 256];   // 32 KB
  __shared__ ushort Bs[64 * 256];   // 32 KB
  int tid = threadIdx.x;
  int blk = blockIdx.x;
  int xcd = blk & 7;
  int idx = blk >> 3;                  // 0..511
  int by = xcd * 64 + (idx & 63);      // 0..511
  int bx = idx >> 6;                   // 0..7
  int m0 = by * 64, n0 = bx * 64;

  // stage full K: 64 rows x 32 chunks (16B) per array; coalesced
#pragma unroll
  for (int i = 0; i < 8; ++i) {
    int g = tid + i * 256;
    int r = g >> 5, c = g & 31;
    int cs = c ^ (r & 31);
    *(uint4*)&As[(r * 32 + cs) * 8] = *(const uint4*)&Ab[(size_t)(m0 + r) * 256 + c * 8];
    *(uint4*)&Bs[(r * 32 + cs) * 8] = *(const uint4*)&Bb[(size_t)(n0 + r) * 256 + c * 8];
  }
  __syncthreads();

  int wave = tid >> 6, lane = tid & 63;
  int wm = (wave >> 1) * 32, wn = (wave & 1) * 32;
  int l16 = lane & 15, quad = lane >> 4;

  f32x4_t acc[2][2];
#pragma unroll
  for (int f = 0; f < 2; ++f)
#pragma unroll
    for (int g = 0; g < 2; ++g) acc[f][g] = (f32x4_t){0.f, 0.f, 0.f, 0.f};

  int arow[2] = {wm + l16, wm + 16 + l16};
  int brow[2] = {wn + l16, wn + 16 + l16};

#pragma unroll
  for (int kc = 0; kc < 8; ++kc) {
    int cl = kc * 4 + quad;
    bf16x8_t af[2], bf[2];
#pragma unroll
    for (int f = 0; f < 2; ++f) {
      af[f] = *(const bf16x8_t*)&As[(arow[f] * 32 + (cl ^ (arow[f] & 31))) * 8];
      bf[f] = *(const bf16x8_t*)&Bs[(brow[f] * 32 + (cl ^ (brow[f] & 31))) * 8];
    }
#pragma unroll
    for (int f = 0; f < 2; ++f)
#pragma unroll
      for (int g = 0; g < 2; ++g)
        acc[f][g] = __builtin_amdgcn_mfma_f32_16x16x32_bf16(af[f], bf[g], acc[f][g], 0, 0, 0);
  }
  __syncthreads();   // all LDS reads done; reuse As as C staging

  ushort* Cs = As;   // 64 x CPAD(72) ushorts = 9 KB
#pragma unroll
  for (int g = 0; g < 2; ++g) {
    int col = wn + g * 16 + l16;
    float bias = brel[n0 + col];
#pragma unroll
    for (int f = 0; f < 2; ++f) {
      int rowb = wm + f * 16 + quad * 4;
#pragma unroll
      for (int r = 0; r < 4; ++r) {
        float v = fmaxf(acc[f][g][r] + bias, 0.f);
        Cs[(rowb + r) * CPAD + col] = f2bf(v);
      }
    }
  }
  __syncthreads();
  {
    int r = tid >> 2, co = (tid & 3) * 16;
    uint4 v0 = *(uint4*)&Cs[r * CPAD + co];
    uint4 v1 = *(uint4*)&Cs[r * CPAD + co + 8];
    *(uint4*)&hw[(size_t)(m0 + r) * 512 + n0 + co] = v0;
    *(uint4*)&hw[(size_t)(m0 + r) * 512 + n0 + co + 8] = v1;
  }
}

// ---------------------------------------------------------------------------
// Kernel D+F fused: per node s (softmax of h.Wpool+b), s/s_logits stores,
// out[b,c,:] partials in registers -> plain stores to outpart (no atomics).
// ---------------------------------------------------------------------------
__global__ __launch_bounds__(256) void pool_node(
    const ushort* __restrict__ hw, const float* __restrict__ Wp,
    const float* __restrict__ bp, float* __restrict__ s,
    float* __restrict__ slog, float* __restrict__ outpart,
    float* __restrict__ ssacc) {
  __shared__ float red[4][1024];   // 16 KB
  __shared__ float ssr[4][3];
  int blk = blockIdx.x;            // 512 blocks
  int b = blk >> 6;
  int wave = threadIdx.x >> 6, lane = threadIdx.x & 63;
  int n0 = blk * 64 + wave * 16;
  int f0 = lane * 8;

  float wp0[8], wp1[8];
#pragma unroll
  for (int j = 0; j < 8; ++j) {
    wp0[j] = Wp[(f0 + j) * 2];
    wp1[j] = Wp[(f0 + j) * 2 + 1];
  }
  float bp0 = bp[0], bp1 = bp[1];
  float o0[8] = {0, 0, 0, 0, 0, 0, 0, 0};
  float o1[8] = {0, 0, 0, 0, 0, 0, 0, 0};
  float sa = 0.f, sb = 0.f, sc2 = 0.f;

  for (int i = 0; i < 16; ++i) {
    int n = n0 + i;
    bf16x8_t hv = *(const bf16x8_t*)&hw[(size_t)n * HID + f0];
    const ushort* hp = (const ushort*)&hv;
    float h[8];
    float a0 = 0.f, a1 = 0.f;
#pragma unroll
    for (int j = 0; j < 8; ++j) {
      h[j] = bf2f(hp[j]);
      a0 += h[j] * wp0[j];
      a1 += h[j] * wp1[j];
    }
#pragma unroll
    for (int off = 32; off; off >>= 1) {
      a0 += __shfl_down(a0, off, 64);
      a1 += __shfl_down(a1, off, 64);
    }
    float s0 = 0.f, s1 = 0.f;
    if (lane == 0) {
      float l0 = a0 + bp0, l1 = a1 + bp1;
      slog[n * 2] = l0;
      slog[n * 2 + 1] = l1;
      float m = fmaxf(l0, l1);
      float e0 = expf(l0 - m), e1 = expf(l1 - m);
      float inv = 1.f / (e0 + e1);
      s0 = e0 * inv; s1 = e1 * inv;
      s[n * 2] = s0;
      s[n * 2 + 1] = s1;
      sa += s0 * s0; sb += s0 * s1; sc2 += s1 * s1;
    }
    s0 = __shfl(s0, 0, 64);
    s1 = __shfl(s1, 0, 64);
#pragma unroll
    for (int j = 0; j < 8; ++j) {
      o0[j] += s0 * h[j];
      o1[j] += s1 * h[j];
    }
  }

#pragma unroll
  for (int j = 0; j < 8; ++j) {
    red[wave][f0 + j] = o0[j];
    red[wave][512 + f0 + j] = o1[j];
  }
  if (lane == 0) { ssr[wave][0] = sa; ssr[wave][1] = sb; ssr[wave][2] = sc2; }
  __syncthreads();
  int t = threadIdx.x;
#pragma unroll
  for (int q = 0; q < 4; ++q) {
    int idx = t + q * 256;
    float v = red[0][idx] + red[1][idx] + red[2][idx] + red[3][idx];
    outpart[(size_t)blk * 1024 + idx] = v;
  }
  if (t < 3) {
    float v = ssr[0][t] + ssr[1][t] + ssr[2][t] + ssr[3][t];
    atomicAdd(&ssacc[b * 4 + t], v);
  }
}

// ---------------------------------------------------------------------------
// Kernel E: out_adj_raw[b,i,j] = sum_e w_e * s[src,i] * s[dst,j]
// + mincut_den[b] = sum_e w_e * (s0[src]^2 + s1[src]^2)
// ---------------------------------------------------------------------------
__global__ __launch_bounds__(256) void edge_pass2(
    const int* __restrict__ src, const int* __restrict__ dst,
    const float* __restrict__ ew, const float* __restrict__ s,
    float* __restrict__ oadj, float* __restrict__ mden) {
  int b = blockIdx.x >> 6;
  int sub = blockIdx.x & 63;
  int base = b * EE + sub * 1024;
  float p00 = 0, p01 = 0, p10 = 0, p11 = 0, md = 0;
  for (int i = threadIdx.x; i < 1024; i += 256) {
    int e = base + i;
    int r = src[e], c = dst[e];
    float w = ew[e];
    float s0r = s[r * 2], s1r = s[r * 2 + 1];
    float s0c = s[c * 2], s1c = s[c * 2 + 1];
    p00 += w * s0r * s0c; p01 += w * s0r * s1c;
    p10 += w * s1r * s0c; p11 += w * s1r * s1c;
    md  += w * (s0r * s0r + s1r * s1r);
  }
#pragma unroll
  for (int off = 32; off; off >>= 1) {
    p00 += __shfl_down(p00, off, 64);
    p01 += __shfl_down(p01, off, 64);
    p10 += __shfl_down(p10, off, 64);
    p11 += __shfl_down(p11, off, 64);
    md  += __shfl_down(md,  off, 64);
  }
  __shared__ float red[4][5];
  int wave = threadIdx.x >> 6, lane = threadIdx.x & 63;
  if (lane == 0) {
    red[wave][0] = p00; red[wave][1] = p01;
    red[wave][2] = p10; red[wave][3] = p11;
    red[wave][4] = md;
  }
  __syncthreads();
  if (threadIdx.x < 4) {
    float v = red[0][threadIdx.x] + red[1][threadIdx.x] +
              red[2][threadIdx.x] + red[3][threadIdx.x];
    atomicAdd(&oadj[b * 4 + threadIdx.x], v);
  } else if (threadIdx.x == 4) {
    float v = red[0][4] + red[1][4] + red[2][4] + red[3][4];
    atomicAdd(&mden[b], v);
  }
}

// ---------------------------------------------------------------------------
// Kernel G1: per-graph scalars + build u,v vectors (sums outpart partials).
// ---------------------------------------------------------------------------
__global__ __launch_bounds__(256) void finalize_a(
    const float* __restrict__ outpart, const float* __restrict__ oadj,
    const float* __restrict__ ssacc, const float* __restrict__ mden,
    float* __restrict__ uv, float* __restrict__ dout) {
  __shared__ float sc[2];
  int b = blockIdx.x, t = threadIdx.x;
  if (t == 0) {
    float r00 = oadj[b * 4 + 0], r01 = oadj[b * 4 + 1];
    float r10 = oadj[b * 4 + 2], r11 = oadj[b * 4 + 3];
    atomicAdd(&dout[80], -((r00 + r11) / mden[b]) / (float)BB);
    float a = ssacc[b * 4 + 0], bb = ssacc[b * 4 + 1], c = ssacc[b * 4 + 2];
    float nrm = sqrtf(a * a + 2.f * bb * bb + c * c);
    float q = 0.70710678118654752f;
    float da = a / nrm - q, db = bb / nrm, dc = c / nrm - q;
    atomicAdd(&dout[81], sqrtf(da * da + 2.f * db * db + dc * dc) / (float)BB);
    float d20 = sqrtf(r01) + 1e-15f;
    float d21 = sqrtf(r10) + 1e-15f;
    float oa01 = r01 / (d20 * d21);
    float oa10 = r10 / (d21 * d20);
    dout[65618 + b * 4 + 0] = 0.f;
    dout[65618 + b * 4 + 1] = oa01;
    dout[65618 + b * 4 + 2] = oa10;
    dout[65618 + b * 4 + 3] = 0.f;
    sc[0] = oa01; sc[1] = oa10;
  }
  __syncthreads();
  float oa01 = sc[0], oa10 = sc[1];
  for (int f = t; f < HID; f += 256) {
    float o0 = 0.f, o1 = 0.f;
    for (int i = 0; i < 64; ++i) {
      o0 += outpart[(size_t)(b * 64 + i) * 1024 + f];
      o1 += outpart[(size_t)(b * 64 + i) * 1024 + 512 + f];
    }
    uv[b * HID + f] = oa10 * o1 + oa01 * o0;           // u
    uv[BB * HID + b * HID + f] = o0 + o1;              // v
  }
}

// ---------------------------------------------------------------------------
// Kernel G2: conv3 split-K partials. Grid 128 = kc(16) x fc(8).
// ---------------------------------------------------------------------------
__global__ __launch_bounds__(256) void conv3_part(
    const float* __restrict__ uv, const float* __restrict__ Wrel3,
    const float* __restrict__ Wroot3, float* __restrict__ xmacc) {
  __shared__ float us[8][32], vs[8][32];
  __shared__ float red[4][64][8];
  int blk = blockIdx.x;
  int fc = blk & 7, kc = blk >> 3;
  int t = threadIdx.x;
  {
    int b = t >> 5, k = t & 31;
    us[b][k] = uv[b * HID + kc * 32 + k];
    vs[b][k] = uv[BB * HID + b * HID + kc * 32 + k];
  }
  __syncthreads();
  int f = fc * 64 + (t & 63);
  int ks = t >> 6;                 // 0..3
  float acc[8] = {0, 0, 0, 0, 0, 0, 0, 0};
#pragma unroll
  for (int j = 0; j < 8; ++j) {
    int kl = ks * 8 + j;           // 0..31
    int k = kc * 32 + kl;
    float wr = Wrel3[k * HID + f];
    float wo = Wroot3[k * HID + f];
#pragma unroll
    for (int b = 0; b < 8; ++b)
      acc[b] += us[b][kl] * wr + vs[b][kl] * wo;
  }
#pragma unroll
  for (int b = 0; b < 8; ++b) red[ks][t & 63][b] = acc[b];
  __syncthreads();
  if (ks == 0) {
    int fl = t & 63;
#pragma unroll
    for (int b = 0; b < 8; ++b) {
      float v = red[0][fl][b] + red[1][fl][b] + red[2][fl][b] + red[3][fl][b];
      atomicAdd(&xmacc[b * HID + f], v);
    }
  }
}

// ---------------------------------------------------------------------------
// Kernel G3: lin1 split-K partials; xm = 0.5*xmacc + brel3 at staging.
// ---------------------------------------------------------------------------
__global__ __launch_bounds__(256) void lin1_part(
    const float* __restrict__ xmacc, const float* __restrict__ brel3,
    const float* __restrict__ Wlin1, float* __restrict__ h2acc) {
  __shared__ float xs[8][32];
  __shared__ float red[4][64][8];
  int blk = blockIdx.x;
  int fc = blk & 7, kc = blk >> 3;
  int t = threadIdx.x;
  {
    int b = t >> 5, k = t & 31;
    xs[b][k] = 0.5f * xmacc[b * HID + kc * 32 + k] + brel3[kc * 32 + k];
  }
  __syncthreads();
  int f = fc * 64 + (t & 63);
  int ks = t >> 6;
  float acc[8] = {0, 0, 0, 0, 0, 0, 0, 0};
#pragma unroll
  for (int j = 0; j < 8; ++j) {
    int kl = ks * 8 + j;
    int k = kc * 32 + kl;
    float w = Wlin1[k * HID + f];
#pragma unroll
    for (int b = 0; b < 8; ++b)
      acc[b] += xs[b][kl] * w;
  }
#pragma unroll
  for (int b = 0; b < 8; ++b) red[ks][t & 63][b] = acc[b];
  __syncthreads();
  if (ks == 0) {
    int fl = t & 63;
#pragma unroll
    for (int b = 0; b < 8; ++b) {
      float v = red[0][fl][b] + red[1][fl][b] + red[2][fl][b] + red[3][fl][b];
      atomicAdd(&h2acc[b * HID + f], v);
    }
  }
}

// ---------------------------------------------------------------------------
// Kernel G4: logits + log_softmax; h2 = relu(h2acc + blin1) at staging.
// ---------------------------------------------------------------------------
__global__ __launch_bounds__(256) void head(
    const float* __restrict__ h2acc, const float* __restrict__ blin1,
    const float* __restrict__ Wlin2, const float* __restrict__ blin2,
    float* __restrict__ dout) {
  __shared__ float hs[HID];
  __shared__ float lg[16];
  __shared__ float lse;
  int b = blockIdx.x, t = threadIdx.x;
  for (int i = t; i < HID; i += 256)
    hs[i] = fmaxf(h2acc[b * HID + i] + blin1[i], 0.f);
  __syncthreads();
  int wave = t >> 6, lane = t & 63;
  for (int o = wave; o < OUTC; o += 4) {
    float acc = 0.f;
    for (int k = lane; k < HID; k += 64)
      acc += hs[k] * Wlin2[k * OUTC + o];
#pragma unroll
    for (int off = 32; off; off >>= 1) acc += __shfl_down(acc, off, 64);
    if (lane == 0) lg[o] = acc + blin2[o];
  }
  __syncthreads();
  if (t == 0) {
    float m = lg[0];
    for (int o = 1; o < OUTC; ++o) m = fmaxf(m, lg[o]);
    float se = 0.f;
    for (int o = 0; o < OUTC; ++o) se += expf(lg[o] - m);
    lse = m + logf(se);
  }
  __syncthreads();
  if (t < OUTC) dout[b * OUTC + t] = lg[t] - lse;
}

// ---------------------------------------------------------------------------
// Launcher
// ---------------------------------------------------------------------------
extern "C" void kernel_launch(void* const* d_in, const int* in_sizes, int n_in,
                              void* d_out, int out_size, void* d_ws, size_t ws_size,
                              hipStream_t stream) {
  const float* x      = (const float*)d_in[0];
  const int*   ei     = (const int*)d_in[1];
  const float* ew     = (const float*)d_in[3];
  const float* Wrel1  = (const float*)d_in[4];
  const float* brel1  = (const float*)d_in[5];
  const float* Wroot1 = (const float*)d_in[6];
  const float* Wpool  = (const float*)d_in[7];
  const float* bpool  = (const float*)d_in[8];
  const float* Wrel3  = (const float*)d_in[9];
  const float* brel3  = (const float*)d_in[10];
  const float* Wroot3 = (const float*)d_in[11];
  const float* Wlin1  = (const float*)d_in[12];
  const float* blin1  = (const float*)d_in[13];
  const float* Wlin2  = (const float*)d_in[14];
  const float* blin2  = (const float*)d_in[15];
  float* out = (float*)d_out;
  float* ws  = (float*)d_ws;

  // workspace layout (float units)
  float* oadj  = ws + 40960;                // [40960, 40992)
  float* ssacc = oadj + 32;                 // [40992, 41024)
  float* mden  = ssacc + 32;                // [41024, 41032)
  int*   deg   = (int*)(mden + 8);          // [41032, 73800)  zero-region end
  ushort* Ab   = (ushort*)(ws + 106568);    // 32768x256 bf16  [106568, 4300872)
  ushort* Bb   = (ushort*)(ws + 4300872);   // 512x256 bf16    [4300872, 4366408)
  ushort* hbf  = (ushort*)(ws + 4366408);   // 32768x512 bf16  [4366408, 12755016)
  float* xmacc = ws + 12755016;             // 4096
  float* h2acc = xmacc + 4096;              // 4096            [12759112, 12763208)
  float* outpart = ws + 12763208;           // 512*1024        [12763208, 13287496)
  // aliases (lifetimes by stream order):
  int2*  ell   = (int2*)(ws + 4366408);     // 32768*64 int2 (16.8MB) inside h region,
                                            // dead before gemm writes hbf
  float* s     = ws + 106568;               // overlays Ab; Ab dead after gemm
  float* uv    = (float*)deg;               // deg dead after gather_ell

  const int* src = ei;
  const int* dst = ei + BE;

  hipMemsetAsync(ws + 40960, 0, (size_t)32840 * sizeof(float), stream);
  hipMemsetAsync(xmacc, 0, (size_t)8192 * sizeof(float), stream);
  hipMemsetAsync(out + 80, 0, 2 * sizeof(float), stream);

  front      <<<6656, 256, 0, stream>>>(src, dst, ew, x, Wrel1, Wroot1,
                                        deg, ell, Ab, Bb);
  gather_ell <<<BN / 4, 256, 0, stream>>>(deg, ell, Ab);
  gemm_mfma  <<<4096, 256, 0, stream>>>(Ab, Bb, brel1, hbf);
  pool_node  <<<512, 256, 0, stream>>>(hbf, Wpool, bpool, s, out + 82, outpart, ssacc);
  edge_pass2 <<<BB * 64, 256, 0, stream>>>(src, dst, ew, s, oadj, mden);
  finalize_a <<<BB, 256, 0, stream>>>(outpart, oadj, ssacc, mden, uv, out);
  conv3_part <<<128, 256, 0, stream>>>(uv, Wrel3, Wroot3, xmacc);
  lin1_part  <<<128, 256, 0, stream>>>(xmacc, brel3, Wlin1, h2acc);
  head       <<<BB, 256, 0, stream>>>(h2acc, blin1, Wlin2, blin2, out);
}

// Round 14
// 231.656 us; speedup vs baseline: 1.0935x; 1.0353x over previous
//
#include <hip/hip_runtime.h>
#include <hip/hip_bf16.h>

// Problem constants
#define BB 8
#define NN 4096
#define EE 65536            // edges per graph
#define BE (BB*EE)          // 524288 total edges
#define BN (BB*NN)          // 32768 total nodes
#define INF 128
#define HID 512
#define CC 2
#define OUTC 10
#define ELLCAP 64           // max in-degree capacity (Binomial mean 16, P(>=64)<1e-13)

typedef __bf16 bf16x8_t __attribute__((ext_vector_type(8)));
typedef float  f32x4_t  __attribute__((ext_vector_type(4)));

__device__ __forceinline__ ushort f2bf(float f) {
  union { float f; unsigned u; } v; v.f = f;
  unsigned r = v.u + 0x7FFFu + ((v.u >> 16) & 1u);   // RNE
  return (ushort)(r >> 16);
}
__device__ __forceinline__ float bf2f(ushort s) {
  union { unsigned u; float f; } v; v.u = ((unsigned)s) << 16;
  return v.f;
}

// ---------------------------------------------------------------------------
// Kernel FRONT (fused): three independent prep stages in one launch.
//   blk <  4096        : cast_x  (x fp32 -> Ab[:,128:256] bf16)
//   4096 <= blk < 6144 : ell_build (one 8B int2 store per edge, 1 atomic)
//   6144 <= blk        : cast_w  (pre-transposed bf16 weights)
// ---------------------------------------------------------------------------
__global__ __launch_bounds__(256) void front(
    const int* __restrict__ src, const int* __restrict__ dst,
    const float* __restrict__ ew, const float* __restrict__ x,
    const float* __restrict__ Wrel, const float* __restrict__ Wroot,
    int* __restrict__ deg, int2* __restrict__ ell,
    ushort* __restrict__ Ab, ushort* __restrict__ Bb) {
  int blk = blockIdx.x;
  int tid = threadIdx.x;
  if (blk < 4096) {
    int g = blk * 256 + tid;                   // 0..1048575
    float4 v = *(const float4*)&x[(size_t)g * 4];
    int m = g >> 5;
    int kin = (g & 31) * 4;
    ushort4 o;
    o.x = f2bf(v.x); o.y = f2bf(v.y); o.z = f2bf(v.z); o.w = f2bf(v.w);
    *(ushort4*)&Ab[(size_t)m * 256 + 128 + kin] = o;
  } else if (blk < 6144) {
    int e = (blk - 4096) * 256 + tid;          // 0..524287
    int d = dst[e];
    int p = atomicAdd(&deg[d], 1);
    if (p < ELLCAP) {
      int2 v; v.x = src[e]; v.y = __float_as_int(ew[e]);
      ell[(size_t)d * ELLCAP + p] = v;
    }
  } else {
    int g = (blk - 6144) * 256 + tid;          // 0..131071
    int n = g & 511, k = g >> 9;
    float w = (k < 128) ? Wrel[k * 512 + n] : Wroot[(k - 128) * 512 + n];
    Bb[n * 256 + k] = f2bf(w);
  }
}

// ---------------------------------------------------------------------------
// Kernel A4: gather  A[n, 0:128] = bf16( sum_j w_j * xbf16[src_j,:] )
// ELL entries packed int2 (src, w-bits); 4-deep independent-load unroll.
// ---------------------------------------------------------------------------
__global__ __launch_bounds__(256) void gather_ell(
    const int* __restrict__ deg, const int2* __restrict__ ell,
    ushort* __restrict__ Ab) {
  int n = blockIdx.x * 4 + (threadIdx.x >> 6);
  int lane = threadIdx.x & 63;
  int d = deg[n]; if (d > ELLCAP) d = ELLCAP;
  const int2* ep = ell + (size_t)n * ELLCAP;
  float ax = 0.f, ay = 0.f;
  int j = 0;
  for (; j + 3 < d; j += 4) {
    int2 v0 = ep[j], v1 = ep[j + 1], v2 = ep[j + 2], v3 = ep[j + 3];
    ushort2 u0 = *(const ushort2*)&Ab[(size_t)v0.x * 256 + 128 + lane * 2];
    ushort2 u1 = *(const ushort2*)&Ab[(size_t)v1.x * 256 + 128 + lane * 2];
    ushort2 u2 = *(const ushort2*)&Ab[(size_t)v2.x * 256 + 128 + lane * 2];
    ushort2 u3 = *(const ushort2*)&Ab[(size_t)v3.x * 256 + 128 + lane * 2];
    float w0 = __int_as_float(v0.y), w1 = __int_as_float(v1.y);
    float w2 = __int_as_float(v2.y), w3 = __int_as_float(v3.y);
    ax += w0 * bf2f(u0.x) + w1 * bf2f(u1.x) + w2 * bf2f(u2.x) + w3 * bf2f(u3.x);
    ay += w0 * bf2f(u0.y) + w1 * bf2f(u1.y) + w2 * bf2f(u2.y) + w3 * bf2f(u3.y);
  }
  for (; j < d; ++j) {
    int2 v0 = ep[j];
    float w0 = __int_as_float(v0.y);
    ushort2 u0 = *(const ushort2*)&Ab[(size_t)v0.x * 256 + 128 + lane * 2];
    ax += w0 * bf2f(u0.x);
    ay += w0 * bf2f(u0.y);
  }
  ushort2 o; o.x = f2bf(ax); o.y = f2bf(ay);
  *(ushort2*)&Ab[(size_t)n * 256 + lane * 2] = o;
}

// ---------------------------------------------------------------------------
// Kernel C: single-stage MFMA GEMM (R13 validated). 64x64 tile, FULL K=256
// staged once for A and B (coalesced, XOR-swizzled, 64 KB, 2 blocks/CU),
// ONE barrier before MFMA. Coalesced C epilogue via CPAD=72 LDS staging.
// ---------------------------------------------------------------------------
#define CPAD 72
__global__ __launch_bounds__(256) void gemm_mfma(
    const ushort* __restrict__ Ab, const ushort* __restrict__ Bb,
    const float* __restrict__ brel, ushort* __restrict__ hw) {
  __shared__ ushort As[64 * 256];   // 32 KB
  __shared__ ushort Bs[64 * 256];   // 32 KB
  int tid = threadIdx.x;
  int blk = blockIdx.x;
  int xcd = blk & 7;
  int idx = blk >> 3;                  // 0..511
  int by = xcd * 64 + (idx & 63);      // 0..511
  int bx = idx >> 6;                   // 0..7
  int m0 = by * 64, n0 = bx * 64;

#pragma unroll
  for (int i = 0; i < 8; ++i) {
    int g = tid + i * 256;
    int r = g >> 5, c = g & 31;
    int cs = c ^ (r & 31);
    *(uint4*)&As[(r * 32 + cs) * 8] = *(const uint4*)&Ab[(size_t)(m0 + r) * 256 + c * 8];
    *(uint4*)&Bs[(r * 32 + cs) * 8] = *(const uint4*)&Bb[(size_t)(n0 + r) * 256 + c * 8];
  }
  __syncthreads();

  int wave = tid >> 6, lane = tid & 63;
  int wm = (wave >> 1) * 32, wn = (wave & 1) * 32;
  int l16 = lane & 15, quad = lane >> 4;

  f32x4_t acc[2][2];
#pragma unroll
  for (int f = 0; f < 2; ++f)
#pragma unroll
    for (int g = 0; g < 2; ++g) acc[f][g] = (f32x4_t){0.f, 0.f, 0.f, 0.f};

  int arow[2] = {wm + l16, wm + 16 + l16};
  int brow[2] = {wn + l16, wn + 16 + l16};

#pragma unroll
  for (int kc = 0; kc < 8; ++kc) {
    int cl = kc * 4 + quad;
    bf16x8_t af[2], bf[2];
#pragma unroll
    for (int f = 0; f < 2; ++f) {
      af[f] = *(const bf16x8_t*)&As[(arow[f] * 32 + (cl ^ (arow[f] & 31))) * 8];
      bf[f] = *(const bf16x8_t*)&Bs[(brow[f] * 32 + (cl ^ (brow[f] & 31))) * 8];
    }
#pragma unroll
    for (int f = 0; f < 2; ++f)
#pragma unroll
      for (int g = 0; g < 2; ++g)
        acc[f][g] = __builtin_amdgcn_mfma_f32_16x16x32_bf16(af[f], bf[g], acc[f][g], 0, 0, 0);
  }
  __syncthreads();   // all LDS reads done; reuse As as C staging

  ushort* Cs = As;   // 64 x CPAD(72) ushorts = 9 KB
#pragma unroll
  for (int g = 0; g < 2; ++g) {
    int col = wn + g * 16 + l16;
    float bias = brel[n0 + col];
#pragma unroll
    for (int f = 0; f < 2; ++f) {
      int rowb = wm + f * 16 + quad * 4;
#pragma unroll
      for (int r = 0; r < 4; ++r) {
        float v = fmaxf(acc[f][g][r] + bias, 0.f);
        Cs[(rowb + r) * CPAD + col] = f2bf(v);
      }
    }
  }
  __syncthreads();
  {
    int r = tid >> 2, co = (tid & 3) * 16;
    uint4 v0 = *(uint4*)&Cs[r * CPAD + co];
    uint4 v1 = *(uint4*)&Cs[r * CPAD + co + 8];
    *(uint4*)&hw[(size_t)(m0 + r) * 512 + n0 + co] = v0;
    *(uint4*)&hw[(size_t)(m0 + r) * 512 + n0 + co + 8] = v1;
  }
}

// ---------------------------------------------------------------------------
// Kernel D+F fused: per node s (softmax of h.Wpool+b), s/s_logits stores,
// out[b,c,:] partials in registers -> plain stores to outpart (no atomics).
// ---------------------------------------------------------------------------
__global__ __launch_bounds__(256) void pool_node(
    const ushort* __restrict__ hw, const float* __restrict__ Wp,
    const float* __restrict__ bp, float* __restrict__ s,
    float* __restrict__ slog, float* __restrict__ outpart,
    float* __restrict__ ssacc) {
  __shared__ float red[4][1024];   // 16 KB
  __shared__ float ssr[4][3];
  int blk = blockIdx.x;            // 512 blocks
  int b = blk >> 6;
  int wave = threadIdx.x >> 6, lane = threadIdx.x & 63;
  int n0 = blk * 64 + wave * 16;
  int f0 = lane * 8;

  float wp0[8], wp1[8];
#pragma unroll
  for (int j = 0; j < 8; ++j) {
    wp0[j] = Wp[(f0 + j) * 2];
    wp1[j] = Wp[(f0 + j) * 2 + 1];
  }
  float bp0 = bp[0], bp1 = bp[1];
  float o0[8] = {0, 0, 0, 0, 0, 0, 0, 0};
  float o1[8] = {0, 0, 0, 0, 0, 0, 0, 0};
  float sa = 0.f, sb = 0.f, sc2 = 0.f;

  for (int i = 0; i < 16; ++i) {
    int n = n0 + i;
    bf16x8_t hv = *(const bf16x8_t*)&hw[(size_t)n * HID + f0];
    const ushort* hp = (const ushort*)&hv;
    float h[8];
    float a0 = 0.f, a1 = 0.f;
#pragma unroll
    for (int j = 0; j < 8; ++j) {
      h[j] = bf2f(hp[j]);
      a0 += h[j] * wp0[j];
      a1 += h[j] * wp1[j];
    }
#pragma unroll
    for (int off = 32; off; off >>= 1) {
      a0 += __shfl_down(a0, off, 64);
      a1 += __shfl_down(a1, off, 64);
    }
    float s0 = 0.f, s1 = 0.f;
    if (lane == 0) {
      float l0 = a0 + bp0, l1 = a1 + bp1;
      slog[n * 2] = l0;
      slog[n * 2 + 1] = l1;
      float m = fmaxf(l0, l1);
      float e0 = expf(l0 - m), e1 = expf(l1 - m);
      float inv = 1.f / (e0 + e1);
      s0 = e0 * inv; s1 = e1 * inv;
      s[n * 2] = s0;
      s[n * 2 + 1] = s1;
      sa += s0 * s0; sb += s0 * s1; sc2 += s1 * s1;
    }
    s0 = __shfl(s0, 0, 64);
    s1 = __shfl(s1, 0, 64);
#pragma unroll
    for (int j = 0; j < 8; ++j) {
      o0[j] += s0 * h[j];
      o1[j] += s1 * h[j];
    }
  }

#pragma unroll
  for (int j = 0; j < 8; ++j) {
    red[wave][f0 + j] = o0[j];
    red[wave][512 + f0 + j] = o1[j];
  }
  if (lane == 0) { ssr[wave][0] = sa; ssr[wave][1] = sb; ssr[wave][2] = sc2; }
  __syncthreads();
  int t = threadIdx.x;
#pragma unroll
  for (int q = 0; q < 4; ++q) {
    int idx = t + q * 256;
    float v = red[0][idx] + red[1][idx] + red[2][idx] + red[3][idx];
    outpart[(size_t)blk * 1024 + idx] = v;
  }
  if (t < 3) {
    float v = ssr[0][t] + ssr[1][t] + ssr[2][t] + ssr[3][t];
    atomicAdd(&ssacc[b * 4 + t], v);
  }
}

// ---------------------------------------------------------------------------
// Kernel E: out_adj_raw[b,i,j] = sum_e w_e * s[src,i] * s[dst,j]
// + mincut_den[b] = sum_e w_e * (s0[src]^2 + s1[src]^2)
// ---------------------------------------------------------------------------
__global__ __launch_bounds__(256) void edge_pass2(
    const int* __restrict__ src, const int* __restrict__ dst,
    const float* __restrict__ ew, const float* __restrict__ s,
    float* __restrict__ oadj, float* __restrict__ mden) {
  int b = blockIdx.x >> 6;
  int sub = blockIdx.x & 63;
  int base = b * EE + sub * 1024;
  float p00 = 0, p01 = 0, p10 = 0, p11 = 0, md = 0;
  for (int i = threadIdx.x; i < 1024; i += 256) {
    int e = base + i;
    int r = src[e], c = dst[e];
    float w = ew[e];
    float s0r = s[r * 2], s1r = s[r * 2 + 1];
    float s0c = s[c * 2], s1c = s[c * 2 + 1];
    p00 += w * s0r * s0c; p01 += w * s0r * s1c;
    p10 += w * s1r * s0c; p11 += w * s1r * s1c;
    md  += w * (s0r * s0r + s1r * s1r);
  }
#pragma unroll
  for (int off = 32; off; off >>= 1) {
    p00 += __shfl_down(p00, off, 64);
    p01 += __shfl_down(p01, off, 64);
    p10 += __shfl_down(p10, off, 64);
    p11 += __shfl_down(p11, off, 64);
    md  += __shfl_down(md,  off, 64);
  }
  __shared__ float red[4][5];
  int wave = threadIdx.x >> 6, lane = threadIdx.x & 63;
  if (lane == 0) {
    red[wave][0] = p00; red[wave][1] = p01;
    red[wave][2] = p10; red[wave][3] = p11;
    red[wave][4] = md;
  }
  __syncthreads();
  if (threadIdx.x < 4) {
    float v = red[0][threadIdx.x] + red[1][threadIdx.x] +
              red[2][threadIdx.x] + red[3][threadIdx.x];
    atomicAdd(&oadj[b * 4 + threadIdx.x], v);
  } else if (threadIdx.x == 4) {
    float v = red[0][4] + red[1][4] + red[2][4] + red[3][4];
    atomicAdd(&mden[b], v);
  }
}

// ---------------------------------------------------------------------------
// Kernel G1: per-graph scalars + build u,v vectors (sums outpart partials).
// ---------------------------------------------------------------------------
__global__ __launch_bounds__(256) void finalize_a(
    const float* __restrict__ outpart, const float* __restrict__ oadj,
    const float* __restrict__ ssacc, const float* __restrict__ mden,
    float* __restrict__ uv, float* __restrict__ dout) {
  __shared__ float sc[2];
  int b = blockIdx.x, t = threadIdx.x;
  if (t == 0) {
    float r00 = oadj[b * 4 + 0], r01 = oadj[b * 4 + 1];
    float r10 = oadj[b * 4 + 2], r11 = oadj[b * 4 + 3];
    atomicAdd(&dout[80], -((r00 + r11) / mden[b]) / (float)BB);
    float a = ssacc[b * 4 + 0], bb = ssacc[b * 4 + 1], c = ssacc[b * 4 + 2];
    float nrm = sqrtf(a * a + 2.f * bb * bb + c * c);
    float q = 0.70710678118654752f;
    float da = a / nrm - q, db = bb / nrm, dc = c / nrm - q;
    atomicAdd(&dout[81], sqrtf(da * da + 2.f * db * db + dc * dc) / (float)BB);
    float d20 = sqrtf(r01) + 1e-15f;
    float d21 = sqrtf(r10) + 1e-15f;
    float oa01 = r01 / (d20 * d21);
    float oa10 = r10 / (d21 * d20);
    dout[65618 + b * 4 + 0] = 0.f;
    dout[65618 + b * 4 + 1] = oa01;
    dout[65618 + b * 4 + 2] = oa10;
    dout[65618 + b * 4 + 3] = 0.f;
    sc[0] = oa01; sc[1] = oa10;
  }
  __syncthreads();
  float oa01 = sc[0], oa10 = sc[1];
  for (int f = t; f < HID; f += 256) {
    float o0 = 0.f, o1 = 0.f;
    for (int i = 0; i < 64; ++i) {
      o0 += outpart[(size_t)(b * 64 + i) * 1024 + f];
      o1 += outpart[(size_t)(b * 64 + i) * 1024 + 512 + f];
    }
    uv[b * HID + f] = oa10 * o1 + oa01 * o0;           // u
    uv[BB * HID + b * HID + f] = o0 + o1;              // v
  }
}

// ---------------------------------------------------------------------------
// Kernel G2: conv3 split-K partials. Grid 128 = kc(16) x fc(8).
// ---------------------------------------------------------------------------
__global__ __launch_bounds__(256) void conv3_part(
    const float* __restrict__ uv, const float* __restrict__ Wrel3,
    const float* __restrict__ Wroot3, float* __restrict__ xmacc) {
  __shared__ float us[8][32], vs[8][32];
  __shared__ float red[4][64][8];
  int blk = blockIdx.x;
  int fc = blk & 7, kc = blk >> 3;
  int t = threadIdx.x;
  {
    int b = t >> 5, k = t & 31;
    us[b][k] = uv[b * HID + kc * 32 + k];
    vs[b][k] = uv[BB * HID + b * HID + kc * 32 + k];
  }
  __syncthreads();
  int f = fc * 64 + (t & 63);
  int ks = t >> 6;                 // 0..3
  float acc[8] = {0, 0, 0, 0, 0, 0, 0, 0};
#pragma unroll
  for (int j = 0; j < 8; ++j) {
    int kl = ks * 8 + j;           // 0..31
    int k = kc * 32 + kl;
    float wr = Wrel3[k * HID + f];
    float wo = Wroot3[k * HID + f];
#pragma unroll
    for (int b = 0; b < 8; ++b)
      acc[b] += us[b][kl] * wr + vs[b][kl] * wo;
  }
#pragma unroll
  for (int b = 0; b < 8; ++b) red[ks][t & 63][b] = acc[b];
  __syncthreads();
  if (ks == 0) {
    int fl = t & 63;
#pragma unroll
    for (int b = 0; b < 8; ++b) {
      float v = red[0][fl][b] + red[1][fl][b] + red[2][fl][b] + red[3][fl][b];
      atomicAdd(&xmacc[b * HID + f], v);
    }
  }
}

// ---------------------------------------------------------------------------
// Kernel G3: lin1 split-K partials; xm = 0.5*xmacc + brel3 at staging.
// ---------------------------------------------------------------------------
__global__ __launch_bounds__(256) void lin1_part(
    const float* __restrict__ xmacc, const float* __restrict__ brel3,
    const float* __restrict__ Wlin1, float* __restrict__ h2acc) {
  __shared__ float xs[8][32];
  __shared__ float red[4][64][8];
  int blk = blockIdx.x;
  int fc = blk & 7, kc = blk >> 3;
  int t = threadIdx.x;
  {
    int b = t >> 5, k = t & 31;
    xs[b][k] = 0.5f * xmacc[b * HID + kc * 32 + k] + brel3[kc * 32 + k];
  }
  __syncthreads();
  int f = fc * 64 + (t & 63);
  int ks = t >> 6;
  float acc[8] = {0, 0, 0, 0, 0, 0, 0, 0};
#pragma unroll
  for (int j = 0; j < 8; ++j) {
    int kl = ks * 8 + j;
    int k = kc * 32 + kl;
    float w = Wlin1[k * HID + f];
#pragma unroll
    for (int b = 0; b < 8; ++b)
      acc[b] += xs[b][kl] * w;
  }
#pragma unroll
  for (int b = 0; b < 8; ++b) red[ks][t & 63][b] = acc[b];
  __syncthreads();
  if (ks == 0) {
    int fl = t & 63;
#pragma unroll
    for (int b = 0; b < 8; ++b) {
      float v = red[0][fl][b] + red[1][fl][b] + red[2][fl][b] + red[3][fl][b];
      atomicAdd(&h2acc[b * HID + f], v);
    }
  }
}

// ---------------------------------------------------------------------------
// Kernel G4: logits + log_softmax; h2 = relu(h2acc + blin1) at staging.
// ---------------------------------------------------------------------------
__global__ __launch_bounds__(256) void head(
    const float* __restrict__ h2acc, const float* __restrict__ blin1,
    const float* __restrict__ Wlin2, const float* __restrict__ blin2,
    float* __restrict__ dout) {
  __shared__ float hs[HID];
  __shared__ float lg[16];
  __shared__ float lse;
  int b = blockIdx.x, t = threadIdx.x;
  for (int i = t; i < HID; i += 256)
    hs[i] = fmaxf(h2acc[b * HID + i] + blin1[i], 0.f);
  __syncthreads();
  int wave = t >> 6, lane = t & 63;
  for (int o = wave; o < OUTC; o += 4) {
    float acc = 0.f;
    for (int k = lane; k < HID; k += 64)
      acc += hs[k] * Wlin2[k * OUTC + o];
#pragma unroll
    for (int off = 32; off; off >>= 1) acc += __shfl_down(acc, off, 64);
    if (lane == 0) lg[o] = acc + blin2[o];
  }
  __syncthreads();
  if (t == 0) {
    float m = lg[0];
    for (int o = 1; o < OUTC; ++o) m = fmaxf(m, lg[o]);
    float se = 0.f;
    for (int o = 0; o < OUTC; ++o) se += expf(lg[o] - m);
    lse = m + logf(se);
  }
  __syncthreads();
  if (t < OUTC) dout[b * OUTC + t] = lg[t] - lse;
}

// ---------------------------------------------------------------------------
// Launcher
// ---------------------------------------------------------------------------
extern "C" void kernel_launch(void* const* d_in, const int* in_sizes, int n_in,
                              void* d_out, int out_size, void* d_ws, size_t ws_size,
                              hipStream_t stream) {
  const float* x      = (const float*)d_in[0];
  const int*   ei     = (const int*)d_in[1];
  const float* ew     = (const float*)d_in[3];
  const float* Wrel1  = (const float*)d_in[4];
  const float* brel1  = (const float*)d_in[5];
  const float* Wroot1 = (const float*)d_in[6];
  const float* Wpool  = (const float*)d_in[7];
  const float* bpool  = (const float*)d_in[8];
  const float* Wrel3  = (const float*)d_in[9];
  const float* brel3  = (const float*)d_in[10];
  const float* Wroot3 = (const float*)d_in[11];
  const float* Wlin1  = (const float*)d_in[12];
  const float* blin1  = (const float*)d_in[13];
  const float* Wlin2  = (const float*)d_in[14];
  const float* blin2  = (const float*)d_in[15];
  float* out = (float*)d_out;
  float* ws  = (float*)d_ws;

  // workspace layout (float units) — zero region is one contiguous block:
  //   [40960, 81992): oadj, ssacc, mden, deg, xmacc, h2acc
  float* oadj  = ws + 40960;                // [40960, 40992)
  float* ssacc = oadj + 32;                 // [40992, 41024)
  float* mden  = ssacc + 32;                // [41024, 41032)
  int*   deg   = (int*)(mden + 8);          // [41032, 73800)
  float* xmacc = ws + 73800;                // [73800, 77896)
  float* h2acc = xmacc + 4096;              // [77896, 81992)  zero-region end
  ushort* Ab   = (ushort*)(ws + 106568);    // 32768x256 bf16  [106568, 4300872)
  ushort* Bb   = (ushort*)(ws + 4300872);   // 512x256 bf16    [4300872, 4366408)
  ushort* hbf  = (ushort*)(ws + 4366408);   // 32768x512 bf16  [4366408, 12755016)
  float* outpart = ws + 12763208;           // 512*1024        [12763208, 13287496)
  // aliases (lifetimes by stream order):
  int2*  ell   = (int2*)(ws + 4366408);     // 32768*64 int2 (16.8MB) inside h region,
                                            // dead before gemm writes hbf
  float* s     = ws + 106568;               // overlays Ab; Ab dead after gemm
  float* uv    = (float*)deg;               // deg dead after gather_ell

  const int* src = ei;
  const int* dst = ei + BE;

  hipMemsetAsync(ws + 40960, 0, (size_t)41032 * sizeof(float), stream);
  hipMemsetAsync(out + 80, 0, 2 * sizeof(float), stream);

  front      <<<6656, 256, 0, stream>>>(src, dst, ew, x, Wrel1, Wroot1,
                                        deg, ell, Ab, Bb);
  gather_ell <<<BN / 4, 256, 0, stream>>>(deg, ell, Ab);
  gemm_mfma  <<<4096, 256, 0, stream>>>(Ab, Bb, brel1, hbf);
  pool_node  <<<512, 256, 0, stream>>>(hbf, Wpool, bpool, s, out + 82, outpart, ssacc);
  edge_pass2 <<<BB * 64, 256, 0, stream>>>(src, dst, ew, s, oadj, mden);
  finalize_a <<<BB, 256, 0, stream>>>(outpart, oadj, ssacc, mden, uv, out);
  conv3_part <<<128, 256, 0, stream>>>(uv, Wrel3, Wroot3, xmacc);
  lin1_part  <<<128, 256, 0, stream>>>(xmacc, brel3, Wlin1, h2acc);
  head       <<<BB, 256, 0, stream>>>(h2acc, blin1, Wlin2, blin2, out);
}